// Round 1
// baseline (653.375 us; speedup 1.0000x reference)
//
#include <hip/hip_runtime.h>
#include <hip/hip_bf16.h>
#include <math.h>
#include <stdint.h>

typedef __attribute__((ext_vector_type(8))) short s16x8;
typedef __attribute__((ext_vector_type(4))) float f32x4;
typedef unsigned int u32;
typedef unsigned short u16;

#define DEVINL __device__ __forceinline__

DEVINL u16 f2bf(float f) {
    u32 b = __builtin_bit_cast(u32, f);
    u32 r = (b + 0x7fffu + ((b >> 16) & 1u)) >> 16;
    return (u16)r;
}

DEVINL void gload_lds16(const void* g, const void* l) {
    __builtin_amdgcn_global_load_lds(
        (const __attribute__((address_space(1))) u32*)(uintptr_t)g,
        (__attribute__((address_space(3))) u32*)(uintptr_t)l, 16, 0, 0);
}

// ---------------- elementwise f32 -> bf16 ----------------
__global__ __launch_bounds__(256)
void cvt_bf16_kernel(const float* __restrict__ in, u16* __restrict__ out, int n4)
{
    int i = blockIdx.x * 256 + threadIdx.x;
    const int stride = gridDim.x * 256;
    for (; i < n4; i += stride) {
        float4 v = ((const float4*)in)[i];
        ushort4 o;
        o.x = f2bf(v.x); o.y = f2bf(v.y); o.z = f2bf(v.z); o.w = f2bf(v.w);
        ((ushort4*)out)[i] = o;
    }
}

// ------------- transpose + convert weights: src[R][C] f32 -> dst[C][R] bf16 -------------
__global__ __launch_bounds__(256)
void transpose_cvt(const float* __restrict__ src, u16* __restrict__ dst, int R, int C)
{
    __shared__ float tile[64][65];
    const int t = threadIdx.x;
    const int c0 = blockIdx.x * 64, r0 = blockIdx.y * 64;
    const int rr = t >> 6;   // 0..3
    const int cc = t & 63;
    #pragma unroll
    for (int i = 0; i < 16; ++i)
        tile[i * 4 + rr][cc] = src[(size_t)(r0 + i * 4 + rr) * C + c0 + cc];
    __syncthreads();
    #pragma unroll
    for (int i = 0; i < 16; ++i) {
        int orow = i * 4 + rr;           // source col
        dst[(size_t)(c0 + orow) * R + r0 + cc] = f2bf(tile[cc][orow]);
    }
}

// ------------- V transpose: qkv[B,T, 2048+h*64+d] bf16 -> vt[bh, d, t] bf16 -------------
__global__ __launch_bounds__(256)
void vtrans_kernel(const u16* __restrict__ qkv, u16* __restrict__ vt)
{
    __shared__ u16 tile[64][68];
    const int t = threadIdx.x;
    const int st = blockIdx.x;       // T/64
    const int bh = blockIdx.y;       // B*H
    const int b = bh >> 4, h = bh & 15;
    const int s0 = st * 64;
    const int rr = t >> 6, cc = t & 63;
    #pragma unroll
    for (int i = 0; i < 16; ++i) {
        int s = i * 4 + rr;
        tile[s][cc] = qkv[(size_t)(b * 2048 + s0 + s) * 3072 + 2048 + h * 64 + cc];
    }
    __syncthreads();
    #pragma unroll
    for (int i = 0; i < 16; ++i) {
        int d = i * 4 + rr;
        vt[(size_t)(bh * 64 + d) * 2048 + s0 + cc] = tile[cc][d];
    }
}

// ---------------- GEMM: C[M,N] = A[M,K](bf16) * B[N,K]^T(bf16) + bias (+resid) ----------------
// MODE 0: bf16 out, +bias
// MODE 1: bf16 out, +bias, exact GELU
// MODE 2: f32 out,  +bias, +resid (f32)
template<int MODE>
__global__ __launch_bounds__(256)
void gemm_bf16(const u16* __restrict__ A, const u16* __restrict__ B,
               const float* __restrict__ bias, const float* __restrict__ resid,
               u16* __restrict__ obf, float* __restrict__ of32,
               int M, int N, int K)
{
    __shared__ u16 Als[128 * 32];
    __shared__ u16 Bls[128 * 32];
    const int t = threadIdx.x;
    const int lane = t & 63;
    const int w = t >> 6;
    const int wr = w >> 1, wc = w & 1;
    const int g = lane >> 4, lr = lane & 15;
    const int bm = blockIdx.x * 128;
    const int bn = blockIdx.y * 128;

    f32x4 acc[4][4] = {};

    // staging geometry: per thread 16B; tile row = 64B (32 bf16)
    const int r0 = t >> 2;              // 0..63
    const int ce = (t & 3) * 8;         // element col
    const size_t aRow0 = (size_t)(bm + r0) * K + ce;
    const size_t aRow1 = (size_t)(bm + r0 + 64) * K + ce;
    const size_t bRow0 = (size_t)(bn + r0) * K + ce;
    const size_t bRow1 = (size_t)(bn + r0 + 64) * K + ce;
    u16* lA0 = &Als[w * 512];
    u16* lA1 = &Als[2048 + w * 512];
    u16* lB0 = &Bls[w * 512];
    u16* lB1 = &Bls[2048 + w * 512];

    for (int k0 = 0; k0 < K; k0 += 32) {
        __syncthreads();
        gload_lds16(A + aRow0 + k0, lA0);
        gload_lds16(A + aRow1 + k0, lA1);
        gload_lds16(B + bRow0 + k0, lB0);
        gload_lds16(B + bRow1 + k0, lB1);
        __syncthreads();

        s16x8 af[4], bf[4];
        #pragma unroll
        for (int m = 0; m < 4; ++m)
            af[m] = *(const s16x8*)&Als[(wr * 64 + m * 16 + lr) * 32 + g * 8];
        #pragma unroll
        for (int n = 0; n < 4; ++n)
            bf[n] = *(const s16x8*)&Bls[(wc * 64 + n * 16 + lr) * 32 + g * 8];
        #pragma unroll
        for (int m = 0; m < 4; ++m)
            #pragma unroll
            for (int n = 0; n < 4; ++n)
                acc[m][n] = __builtin_amdgcn_mfma_f32_16x16x32_bf16(af[m], bf[n], acc[m][n], 0, 0, 0);
    }

    // epilogue: D layout row = 4*(lane>>4)+reg, col = lane&15
    #pragma unroll
    for (int m = 0; m < 4; ++m) {
        const int rbase = bm + wr * 64 + m * 16 + g * 4;
        #pragma unroll
        for (int n = 0; n < 4; ++n) {
            const int col = bn + wc * 64 + n * 16 + lr;
            const float bia = bias[col];
            #pragma unroll
            for (int b2 = 0; b2 < 4; ++b2) {
                const int r = rbase + b2;
                float v = acc[m][n][b2] + bia;
                if (MODE == 1) v = 0.5f * v * (1.0f + erff(v * 0.70710678118654752f));
                if (MODE == 2) {
                    v += resid[(size_t)r * N + col];
                    of32[(size_t)r * N + col] = v;
                } else {
                    obf[(size_t)r * N + col] = f2bf(v);
                }
            }
        }
    }
}

// ---------------- flash attention: one (b,h) x 64 Q rows per block ----------------
__global__ __launch_bounds__(256)
void attn_kernel(const u16* __restrict__ qkv, const u16* __restrict__ vt,
                 u16* __restrict__ attnb)
{
    __shared__ u16 Kls[64 * 64];
    __shared__ u16 Vls[64 * 64];
    __shared__ u16 Pls[4][16 * 72];
    const int t = threadIdx.x, lane = t & 63, w = t >> 6;
    const int g = lane >> 4, lr = lane & 15;
    const int qt = blockIdx.x;         // T/64
    const int bh = blockIdx.y;         // B*H
    const int b = bh >> 4, h = bh & 15;

    // Q fragments direct from global (A-operand layout is contiguous 16B/lane)
    const int qtok = b * 2048 + qt * 64 + w * 16 + lr;
    const u16* qp = qkv + (size_t)qtok * 3072 + h * 64;
    const s16x8 qf0 = *(const s16x8*)(qp + g * 8);
    const s16x8 qf1 = *(const s16x8*)(qp + 32 + g * 8);

    f32x4 o[4] = {};
    float mreg[4] = {-3e38f, -3e38f, -3e38f, -3e38f};
    float lreg[4] = {0.f, 0.f, 0.f, 0.f};

    // staging geometry: tile rows are 128B (64 bf16), 8 lanes/row
    const int srow = t >> 3;            // 0..31
    const int scol = (t & 7) * 8;
    const size_t kbase0 = (size_t)(b * 2048 + srow) * 3072 + 1024 + h * 64 + scol;
    const size_t kbase1 = (size_t)(b * 2048 + srow + 32) * 3072 + 1024 + h * 64 + scol;
    const size_t vbase0 = (size_t)(bh * 64 + srow) * 2048 + scol;
    const size_t vbase1 = (size_t)(bh * 64 + srow + 32) * 2048 + scol;
    u16* lK0 = &Kls[w * 512]; u16* lK1 = &Kls[2048 + w * 512];
    u16* lV0 = &Vls[w * 512]; u16* lV1 = &Vls[2048 + w * 512];

    for (int s0 = 0; s0 < 2048; s0 += 64) {
        __syncthreads();
        gload_lds16(qkv + kbase0 + (size_t)s0 * 3072, lK0);
        gload_lds16(qkv + kbase1 + (size_t)s0 * 3072, lK1);
        gload_lds16(vt + vbase0 + s0, lV0);
        gload_lds16(vt + vbase1 + s0, lV1);
        __syncthreads();

        // S = Q K^T (per wave: 16 q x 64 s)
        f32x4 sv[4];
        #pragma unroll
        for (int n = 0; n < 4; ++n) {
            const s16x8 k0v = *(const s16x8*)&Kls[(n * 16 + lr) * 64 + g * 8];
            const s16x8 k1v = *(const s16x8*)&Kls[(n * 16 + lr) * 64 + 32 + g * 8];
            f32x4 z = {};
            z = __builtin_amdgcn_mfma_f32_16x16x32_bf16(qf0, k0v, z, 0, 0, 0);
            z = __builtin_amdgcn_mfma_f32_16x16x32_bf16(qf1, k1v, z, 0, 0, 0);
            sv[n] = z;
        }

        // online softmax per row r = 4g + b2 (held at reg b2 across the 16 lanes of group g)
        #pragma unroll
        for (int b2 = 0; b2 < 4; ++b2) {
            float p0 = sv[0][b2] * 0.125f;
            float p1 = sv[1][b2] * 0.125f;
            float p2 = sv[2][b2] * 0.125f;
            float p3 = sv[3][b2] * 0.125f;
            float mx = fmaxf(fmaxf(p0, p1), fmaxf(p2, p3));
            mx = fmaxf(mx, __shfl_xor(mx, 1));
            mx = fmaxf(mx, __shfl_xor(mx, 2));
            mx = fmaxf(mx, __shfl_xor(mx, 4));
            mx = fmaxf(mx, __shfl_xor(mx, 8));
            const float mnew = fmaxf(mreg[b2], mx);
            const float scale = __expf(mreg[b2] - mnew);
            mreg[b2] = mnew;
            p0 = __expf(p0 - mnew);
            p1 = __expf(p1 - mnew);
            p2 = __expf(p2 - mnew);
            p3 = __expf(p3 - mnew);
            float sum = p0 + p1 + p2 + p3;
            sum += __shfl_xor(sum, 1);
            sum += __shfl_xor(sum, 2);
            sum += __shfl_xor(sum, 4);
            sum += __shfl_xor(sum, 8);
            lreg[b2] = lreg[b2] * scale + sum;
            o[0][b2] *= scale; o[1][b2] *= scale; o[2][b2] *= scale; o[3][b2] *= scale;
            const int prow = g * 4 + b2;
            Pls[w][prow * 72 +  0 + lr] = f2bf(p0);
            Pls[w][prow * 72 + 16 + lr] = f2bf(p1);
            Pls[w][prow * 72 + 32 + lr] = f2bf(p2);
            Pls[w][prow * 72 + 48 + lr] = f2bf(p3);
        }
        __syncthreads();

        // O += P V  (A = P from LDS in A-layout; B = V^T tile, contiguous)
        const s16x8 ap0 = *(const s16x8*)&Pls[w][lr * 72 + g * 8];
        const s16x8 ap1 = *(const s16x8*)&Pls[w][lr * 72 + 32 + g * 8];
        #pragma unroll
        for (int n = 0; n < 4; ++n) {
            const s16x8 v0 = *(const s16x8*)&Vls[(n * 16 + lr) * 64 + g * 8];
            const s16x8 v1 = *(const s16x8*)&Vls[(n * 16 + lr) * 64 + 32 + g * 8];
            o[n] = __builtin_amdgcn_mfma_f32_16x16x32_bf16(ap0, v0, o[n], 0, 0, 0);
            o[n] = __builtin_amdgcn_mfma_f32_16x16x32_bf16(ap1, v1, o[n], 0, 0, 0);
        }
    }

    const int orow0 = b * 2048 + qt * 64 + w * 16 + g * 4;
    #pragma unroll
    for (int b2 = 0; b2 < 4; ++b2) {
        const float inv = 1.0f / lreg[b2];
        #pragma unroll
        for (int n = 0; n < 4; ++n)
            attnb[(size_t)(orow0 + b2) * 1024 + h * 64 + n * 16 + lr] = f2bf(o[n][b2] * inv);
    }
}

// ---------------- LayerNorm: f32 in -> bf16 out ----------------
__global__ __launch_bounds__(256)
void ln_kernel(const float* __restrict__ x, const float* __restrict__ lw,
               const float* __restrict__ lb, u16* __restrict__ out)
{
    const int row = blockIdx.x;
    const int t = threadIdx.x;
    const float4 v = ((const float4*)(x + (size_t)row * 1024))[t];
    float s = v.x + v.y + v.z + v.w;
    float s2 = v.x * v.x + v.y * v.y + v.z * v.z + v.w * v.w;
    #pragma unroll
    for (int m = 32; m >= 1; m >>= 1) {
        s  += __shfl_xor(s, m);
        s2 += __shfl_xor(s2, m);
    }
    __shared__ float red[16];
    const int w = t >> 6, lane = t & 63;
    if (lane == 0) { red[w] = s; red[8 + w] = s2; }
    __syncthreads();
    s  = red[0] + red[1] + red[2] + red[3];
    s2 = red[8] + red[9] + red[10] + red[11];
    const float mu = s * (1.0f / 1024.0f);
    const float var = s2 * (1.0f / 1024.0f) - mu * mu;
    const float inv = rsqrtf(var + 1e-5f);
    const float4 wv = ((const float4*)lw)[t];
    const float4 bv = ((const float4*)lb)[t];
    ushort4 oo;
    oo.x = f2bf((v.x - mu) * inv * wv.x + bv.x);
    oo.y = f2bf((v.y - mu) * inv * wv.y + bv.y);
    oo.z = f2bf((v.z - mu) * inv * wv.z + bv.z);
    oo.w = f2bf((v.w - mu) * inv * wv.w + bv.w);
    ((ushort4*)(out + (size_t)row * 1024))[t] = oo;
}

extern "C" void kernel_launch(void* const* d_in, const int* in_sizes, int n_in,
                              void* d_out, int out_size, void* d_ws, size_t ws_size,
                              hipStream_t stream)
{
    const float* x      = (const float*)d_in[0];
    const float* w_attn = (const float*)d_in[1];
    const float* b_attn = (const float*)d_in[2];
    const float* w_o    = (const float*)d_in[3];
    const float* b_o    = (const float*)d_in[4];
    const float* ln_w   = (const float*)d_in[5];
    const float* ln_b   = (const float*)d_in[6];
    const float* w_fc1  = (const float*)d_in[7];
    const float* b_fc1  = (const float*)d_in[8];
    const float* w_fc2  = (const float*)d_in[9];
    const float* b_fc2  = (const float*)d_in[10];
    float* out = (float*)d_out;

    char* ws = (char*)d_ws;
    u16*   xb    = (u16*)(ws);                       // 16 MB  bf16 x
    u16*   wqkvT = (u16*)(ws + 16777216);            //  6 MB  [3072][1024]
    u16*   woT   = (u16*)(ws + 23068672);            //  2 MB  [1024][1024]
    u16*   w1T   = (u16*)(ws + 25165824);            //  8 MB  [4096][1024]
    u16*   w2T   = (u16*)(ws + 33554432);            //  8 MB  [1024][4096]
    float* x1    = (float*)(ws + 41943040);          // 32 MB  f32 residual-1
    u16*   attnb = (u16*)(ws + 75497472);            // 16 MB  (later reused as hb)
    u16*   hb    = attnb;
    u16*   qkvb  = (u16*)(ws + 92274688);            // 48 MB  [8192][3072]
    u16*   vtb   = qkvb + 25165824;                  // 16 MB  [64][64][2048] (elements)
    u16*   h1    = qkvb;                             // 64 MB alias (qkv+vt dead after attn)

    // conversions
    cvt_bf16_kernel<<<2048, 256, 0, stream>>>(x, xb, 8192 * 1024 / 4);
    transpose_cvt<<<dim3(48, 16), 256, 0, stream>>>(w_attn, wqkvT, 1024, 3072);
    transpose_cvt<<<dim3(16, 16), 256, 0, stream>>>(w_o,   woT,  1024, 1024);
    transpose_cvt<<<dim3(64, 16), 256, 0, stream>>>(w_fc1, w1T,  1024, 4096);
    transpose_cvt<<<dim3(16, 64), 256, 0, stream>>>(w_fc2, w2T,  4096, 1024);

    // qkv = x @ w_attn + b_attn
    gemm_bf16<0><<<dim3(64, 24), 256, 0, stream>>>(xb, wqkvT, b_attn, nullptr,
                                                   qkvb, nullptr, 8192, 3072, 1024);
    // V transpose for attention B-operand
    vtrans_kernel<<<dim3(32, 64), 256, 0, stream>>>(qkvb, vtb);
    // attention
    attn_kernel<<<dim3(32, 64), 256, 0, stream>>>(qkvb, vtb, attnb);
    // x1 = attn @ w_o + b_o + x
    gemm_bf16<2><<<dim3(64, 8), 256, 0, stream>>>(attnb, woT, b_o, x,
                                                  nullptr, x1, 8192, 1024, 1024);
    // h = LN(x1)
    ln_kernel<<<8192, 256, 0, stream>>>(x1, ln_w, ln_b, hb);
    // h1 = gelu(h @ w_fc1 + b_fc1)
    gemm_bf16<1><<<dim3(64, 32), 256, 0, stream>>>(hb, w1T, b_fc1, nullptr,
                                                   h1, nullptr, 8192, 4096, 1024);
    // out = h1 @ w_fc2 + b_fc2 + x1
    gemm_bf16<2><<<dim3(64, 8), 256, 0, stream>>>(h1, w2T, b_fc2, x1,
                                                  nullptr, out, 8192, 1024, 4096);
}

// Round 2
// 511.053 us; speedup vs baseline: 1.2785x; 1.2785x over previous
//
#include <hip/hip_runtime.h>
#include <hip/hip_bf16.h>
#include <math.h>
#include <stdint.h>

typedef __attribute__((ext_vector_type(8))) short s16x8;
typedef __attribute__((ext_vector_type(4))) float f32x4;
typedef unsigned int u32;
typedef unsigned short u16;

#define DEVINL __device__ __forceinline__

DEVINL u16 f2bf(float f) {
    u32 b = __builtin_bit_cast(u32, f);
    u32 r = (b + 0x7fffu + ((b >> 16) & 1u)) >> 16;
    return (u16)r;
}

DEVINL float fexp2(float x) {
    float r;
    asm("v_exp_f32 %0, %1" : "=v"(r) : "v"(x));
    return r;
}

DEVINL u32 cvt_pk_bf16(float lo, float hi) {
    u32 r;
    asm("v_cvt_pk_bf16_f32 %0, %1, %2" : "=v"(r) : "v"(lo), "v"(hi));
    return r;
}

DEVINL void gload_lds16(const void* g, const void* l) {
    __builtin_amdgcn_global_load_lds(
        (const __attribute__((address_space(1))) u32*)(uintptr_t)g,
        (__attribute__((address_space(3))) u32*)(uintptr_t)l, 16, 0, 0);
}

// ---------------- elementwise f32 -> bf16 ----------------
__global__ __launch_bounds__(256)
void cvt_bf16_kernel(const float* __restrict__ in, u16* __restrict__ out, int n4)
{
    int i = blockIdx.x * 256 + threadIdx.x;
    const int stride = gridDim.x * 256;
    for (; i < n4; i += stride) {
        float4 v = ((const float4*)in)[i];
        ushort4 o;
        o.x = f2bf(v.x); o.y = f2bf(v.y); o.z = f2bf(v.z); o.w = f2bf(v.w);
        ((ushort4*)out)[i] = o;
    }
}

// ------------- transpose + convert weights: src[R][C] f32 -> dst[C][R] bf16 -------------
__global__ __launch_bounds__(256)
void transpose_cvt(const float* __restrict__ src, u16* __restrict__ dst, int R, int C)
{
    __shared__ float tile[64][65];
    const int t = threadIdx.x;
    const int c0 = blockIdx.x * 64, r0 = blockIdx.y * 64;
    const int rr = t >> 6;   // 0..3
    const int cc = t & 63;
    #pragma unroll
    for (int i = 0; i < 16; ++i)
        tile[i * 4 + rr][cc] = src[(size_t)(r0 + i * 4 + rr) * C + c0 + cc];
    __syncthreads();
    #pragma unroll
    for (int i = 0; i < 16; ++i) {
        int orow = i * 4 + rr;           // source col
        dst[(size_t)(c0 + orow) * R + r0 + cc] = f2bf(tile[cc][orow]);
    }
}

// ------------- V transpose: qkv[B,T, 2048+h*64+d] bf16 -> vt[bh, d, sigma(t)] bf16 -------
// sigma scrambles token order within each 64-token tile so the packed-u32 P layout's
// k-order matches V's k-order for the PV MFMA.
__global__ __launch_bounds__(256)
void vtrans_kernel(const u16* __restrict__ qkv, u16* __restrict__ vt)
{
    __shared__ u16 tile[64][68];
    const int t = threadIdx.x;
    const int st = blockIdx.x;       // T/64
    const int bh = blockIdx.y;       // B*H
    const int b = bh >> 4, h = bh & 15;
    const int s0 = st * 64;
    const int rr = t >> 6, cc = t & 63;
    // sigma(cc): position of token cc inside the 64-token stored tile
    const int sc = (cc & 32) | (((cc & 15) >> 2) << 3) | ((cc & 3) << 1) | ((cc >> 4) & 1);
    #pragma unroll
    for (int i = 0; i < 16; ++i) {
        int s = i * 4 + rr;
        tile[s][cc] = qkv[(size_t)(b * 2048 + s0 + s) * 3072 + 2048 + h * 64 + cc];
    }
    __syncthreads();
    #pragma unroll
    for (int i = 0; i < 16; ++i) {
        int d = i * 4 + rr;
        vt[(size_t)(bh * 64 + d) * 2048 + s0 + sc] = tile[cc][d];
    }
}

// ---------------- GEMM: C[M,N] = A[M,K](bf16) * B[N,K]^T(bf16) + bias (+resid) ----------------
// MODE 0: bf16 out, +bias
// MODE 1: bf16 out, +bias, exact GELU
// MODE 2: f32 out,  +bias, +resid (f32)
template<int MODE>
__global__ __launch_bounds__(256)
void gemm_bf16(const u16* __restrict__ A, const u16* __restrict__ B,
               const float* __restrict__ bias, const float* __restrict__ resid,
               u16* __restrict__ obf, float* __restrict__ of32,
               int M, int N, int K)
{
    __shared__ u16 Als[128 * 32];
    __shared__ u16 Bls[128 * 32];
    const int t = threadIdx.x;
    const int lane = t & 63;
    const int w = t >> 6;
    const int wr = w >> 1, wc = w & 1;
    const int g = lane >> 4, lr = lane & 15;
    const int bm = blockIdx.x * 128;
    const int bn = blockIdx.y * 128;

    f32x4 acc[4][4] = {};

    const int r0 = t >> 2;              // 0..63
    const int ce = (t & 3) * 8;         // element col
    const size_t aRow0 = (size_t)(bm + r0) * K + ce;
    const size_t aRow1 = (size_t)(bm + r0 + 64) * K + ce;
    const size_t bRow0 = (size_t)(bn + r0) * K + ce;
    const size_t bRow1 = (size_t)(bn + r0 + 64) * K + ce;
    u16* lA0 = &Als[w * 512];
    u16* lA1 = &Als[2048 + w * 512];
    u16* lB0 = &Bls[w * 512];
    u16* lB1 = &Bls[2048 + w * 512];

    for (int k0 = 0; k0 < K; k0 += 32) {
        __syncthreads();
        gload_lds16(A + aRow0 + k0, lA0);
        gload_lds16(A + aRow1 + k0, lA1);
        gload_lds16(B + bRow0 + k0, lB0);
        gload_lds16(B + bRow1 + k0, lB1);
        __syncthreads();

        s16x8 af[4], bf[4];
        #pragma unroll
        for (int m = 0; m < 4; ++m)
            af[m] = *(const s16x8*)&Als[(wr * 64 + m * 16 + lr) * 32 + g * 8];
        #pragma unroll
        for (int n = 0; n < 4; ++n)
            bf[n] = *(const s16x8*)&Bls[(wc * 64 + n * 16 + lr) * 32 + g * 8];
        #pragma unroll
        for (int m = 0; m < 4; ++m)
            #pragma unroll
            for (int n = 0; n < 4; ++n)
                acc[m][n] = __builtin_amdgcn_mfma_f32_16x16x32_bf16(af[m], bf[n], acc[m][n], 0, 0, 0);
    }

    #pragma unroll
    for (int m = 0; m < 4; ++m) {
        const int rbase = bm + wr * 64 + m * 16 + g * 4;
        #pragma unroll
        for (int n = 0; n < 4; ++n) {
            const int col = bn + wc * 64 + n * 16 + lr;
            const float bia = bias[col];
            #pragma unroll
            for (int b2 = 0; b2 < 4; ++b2) {
                const int r = rbase + b2;
                float v = acc[m][n][b2] + bia;
                if (MODE == 1) v = 0.5f * v * (1.0f + erff(v * 0.70710678118654752f));
                if (MODE == 2) {
                    v += resid[(size_t)r * N + col];
                    of32[(size_t)r * N + col] = v;
                } else {
                    obf[(size_t)r * N + col] = f2bf(v);
                }
            }
        }
    }
}

// ---------------- flash attention: one (b,h) x 64 Q rows per block ----------------
// K/V LDS tiles are XOR-bank-swizzled: physical element = row*64 + (col ^ ((row&7)*8)).
// Achieved by pre-swizzling the GLOBAL source column at stage time (LDS dest stays
// linear, as global_load_lds requires) and applying the same XOR on the read side.
__global__ __launch_bounds__(256)
void attn_kernel(const u16* __restrict__ qkv, const u16* __restrict__ vt,
                 u16* __restrict__ attnb)
{
    __shared__ u16 Kls[64 * 64];
    __shared__ u16 Vls[64 * 64];
    __shared__ u32 Pls[4][16 * 36];   // per-wave P, packed bf16 pairs, 144B row stride
    const int t = threadIdx.x, lane = t & 63, w = t >> 6;
    const int g = lane >> 4, lr = lane & 15;
    const int qt = blockIdx.x;         // T/64
    const int bh = blockIdx.y;         // B*H
    const int b = bh >> 4, h = bh & 15;

    // Q fragments direct from global (A-operand layout is contiguous 16B/lane)
    const int qtok = b * 2048 + qt * 64 + w * 16 + lr;
    const u16* qp = qkv + (size_t)qtok * 3072 + h * 64;
    const s16x8 qf0 = *(const s16x8*)(qp + g * 8);
    const s16x8 qf1 = *(const s16x8*)(qp + 32 + g * 8);

    f32x4 o[4] = {};
    float lreg[4] = {0.f, 0.f, 0.f, 0.f};

    // staging geometry: 8 lanes/row, 16B/lane; pre-swizzle the source column
    const int srow = t >> 3;                              // 0..31
    const int scol = (((t & 7) ^ (srow & 7)) * 8);        // swizzled element col
    const size_t kbase0 = (size_t)(b * 2048 + srow) * 3072 + 1024 + h * 64 + scol;
    const size_t kbase1 = (size_t)(b * 2048 + srow + 32) * 3072 + 1024 + h * 64 + scol;
    const size_t vbase0 = (size_t)(bh * 64 + srow) * 2048 + scol;
    const size_t vbase1 = (size_t)(bh * 64 + srow + 32) * 2048 + scol;
    u16* lK0 = &Kls[w * 512]; u16* lK1 = &Kls[2048 + w * 512];
    u16* lV0 = &Vls[w * 512]; u16* lV1 = &Vls[2048 + w * 512];

    const int xr = (lr & 7) * 8;       // read-side XOR (row&7)*8; rows are n*16+lr
    const float C2 = 0.18033688011112042f;   // (1/8) * log2(e)

    for (int s0 = 0; s0 < 2048; s0 += 64) {
        __syncthreads();
        gload_lds16(qkv + kbase0 + (size_t)s0 * 3072, lK0);
        gload_lds16(qkv + kbase1 + (size_t)s0 * 3072, lK1);
        gload_lds16(vt + vbase0 + s0, lV0);
        gload_lds16(vt + vbase1 + s0, lV1);
        __syncthreads();

        // S = Q K^T (per wave: 16 q x 64 kv)
        f32x4 sv[4];
        #pragma unroll
        for (int n = 0; n < 4; ++n) {
            const int kr = (n * 16 + lr) * 64;
            const s16x8 k0v = *(const s16x8*)&Kls[kr + ((g * 8) ^ xr)];
            const s16x8 k1v = *(const s16x8*)&Kls[kr + ((32 + g * 8) ^ xr)];
            f32x4 z = {};
            z = __builtin_amdgcn_mfma_f32_16x16x32_bf16(qf0, k0v, z, 0, 0, 0);
            z = __builtin_amdgcn_mfma_f32_16x16x32_bf16(qf1, k1v, z, 0, 0, 0);
            sv[n] = z;
        }

        // max-free softmax accumulate: P = exp2(S * C2); packed-u32 P store
        #pragma unroll
        for (int b2 = 0; b2 < 4; ++b2) {
            const float p0 = fexp2(sv[0][b2] * C2);
            const float p1 = fexp2(sv[1][b2] * C2);
            const float p2 = fexp2(sv[2][b2] * C2);
            const float p3 = fexp2(sv[3][b2] * C2);
            float sum = (p0 + p1) + (p2 + p3);
            sum += __shfl_xor(sum, 1);
            sum += __shfl_xor(sum, 2);
            sum += __shfl_xor(sum, 4);
            sum += __shfl_xor(sum, 8);
            lreg[b2] += sum;
            const int prow = (g * 4 + b2) * 36;
            Pls[w][prow + lr]      = cvt_pk_bf16(p0, p1);  // tokens (lr, lr+16)
            Pls[w][prow + 16 + lr] = cvt_pk_bf16(p2, p3);  // tokens (lr+32, lr+48)
        }
        // no barrier: Pls is per-wave, Vls already synced after staging

        // O += P V   (A = P from per-wave LDS; B = sigma-ordered V^T tile)
        const s16x8 ap0 = *(const s16x8*)&Pls[w][lr * 36 + g * 4];
        const s16x8 ap1 = *(const s16x8*)&Pls[w][lr * 36 + 16 + g * 4];
        #pragma unroll
        for (int n = 0; n < 4; ++n) {
            const int vr = (n * 16 + lr) * 64;
            const s16x8 v0 = *(const s16x8*)&Vls[vr + ((g * 8) ^ xr)];
            const s16x8 v1 = *(const s16x8*)&Vls[vr + ((32 + g * 8) ^ xr)];
            o[n] = __builtin_amdgcn_mfma_f32_16x16x32_bf16(ap0, v0, o[n], 0, 0, 0);
            o[n] = __builtin_amdgcn_mfma_f32_16x16x32_bf16(ap1, v1, o[n], 0, 0, 0);
        }
    }

    const int orow0 = b * 2048 + qt * 64 + w * 16 + g * 4;
    #pragma unroll
    for (int b2 = 0; b2 < 4; ++b2) {
        const float inv = 1.0f / lreg[b2];
        #pragma unroll
        for (int n = 0; n < 4; ++n)
            attnb[(size_t)(orow0 + b2) * 1024 + h * 64 + n * 16 + lr] = f2bf(o[n][b2] * inv);
    }
}

// ---------------- LayerNorm: f32 in -> bf16 out ----------------
__global__ __launch_bounds__(256)
void ln_kernel(const float* __restrict__ x, const float* __restrict__ lw,
               const float* __restrict__ lb, u16* __restrict__ out)
{
    const int row = blockIdx.x;
    const int t = threadIdx.x;
    const float4 v = ((const float4*)(x + (size_t)row * 1024))[t];
    float s = v.x + v.y + v.z + v.w;
    float s2 = v.x * v.x + v.y * v.y + v.z * v.z + v.w * v.w;
    #pragma unroll
    for (int m = 32; m >= 1; m >>= 1) {
        s  += __shfl_xor(s, m);
        s2 += __shfl_xor(s2, m);
    }
    __shared__ float red[16];
    const int w = t >> 6, lane = t & 63;
    if (lane == 0) { red[w] = s; red[8 + w] = s2; }
    __syncthreads();
    s  = red[0] + red[1] + red[2] + red[3];
    s2 = red[8] + red[9] + red[10] + red[11];
    const float mu = s * (1.0f / 1024.0f);
    const float var = s2 * (1.0f / 1024.0f) - mu * mu;
    const float inv = rsqrtf(var + 1e-5f);
    const float4 wv = ((const float4*)lw)[t];
    const float4 bv = ((const float4*)lb)[t];
    ushort4 oo;
    oo.x = f2bf((v.x - mu) * inv * wv.x + bv.x);
    oo.y = f2bf((v.y - mu) * inv * wv.y + bv.y);
    oo.z = f2bf((v.z - mu) * inv * wv.z + bv.z);
    oo.w = f2bf((v.w - mu) * inv * wv.w + bv.w);
    ((ushort4*)(out + (size_t)row * 1024))[t] = oo;
}

extern "C" void kernel_launch(void* const* d_in, const int* in_sizes, int n_in,
                              void* d_out, int out_size, void* d_ws, size_t ws_size,
                              hipStream_t stream)
{
    const float* x      = (const float*)d_in[0];
    const float* w_attn = (const float*)d_in[1];
    const float* b_attn = (const float*)d_in[2];
    const float* w_o    = (const float*)d_in[3];
    const float* b_o    = (const float*)d_in[4];
    const float* ln_w   = (const float*)d_in[5];
    const float* ln_b   = (const float*)d_in[6];
    const float* w_fc1  = (const float*)d_in[7];
    const float* b_fc1  = (const float*)d_in[8];
    const float* w_fc2  = (const float*)d_in[9];
    const float* b_fc2  = (const float*)d_in[10];
    float* out = (float*)d_out;

    char* ws = (char*)d_ws;
    u16*   xb    = (u16*)(ws);                       // 16 MB  bf16 x
    u16*   wqkvT = (u16*)(ws + 16777216);            //  6 MB  [3072][1024]
    u16*   woT   = (u16*)(ws + 23068672);            //  2 MB  [1024][1024]
    u16*   w1T   = (u16*)(ws + 25165824);            //  8 MB  [4096][1024]
    u16*   w2T   = (u16*)(ws + 33554432);            //  8 MB  [1024][4096]
    float* x1    = (float*)(ws + 41943040);          // 32 MB  f32 residual-1
    u16*   attnb = (u16*)(ws + 75497472);            // 16 MB  (later reused as hb)
    u16*   hb    = attnb;
    u16*   qkvb  = (u16*)(ws + 92274688);            // 48 MB  [8192][3072]
    u16*   vtb   = qkvb + 25165824;                  // 16 MB  [64][64][2048] (elements)
    u16*   h1    = qkvb;                             // 64 MB alias (qkv+vt dead after attn)

    // conversions
    cvt_bf16_kernel<<<2048, 256, 0, stream>>>(x, xb, 8192 * 1024 / 4);
    transpose_cvt<<<dim3(48, 16), 256, 0, stream>>>(w_attn, wqkvT, 1024, 3072);
    transpose_cvt<<<dim3(16, 16), 256, 0, stream>>>(w_o,   woT,  1024, 1024);
    transpose_cvt<<<dim3(64, 16), 256, 0, stream>>>(w_fc1, w1T,  1024, 4096);
    transpose_cvt<<<dim3(16, 64), 256, 0, stream>>>(w_fc2, w2T,  4096, 1024);

    // qkv = x @ w_attn + b_attn
    gemm_bf16<0><<<dim3(64, 24), 256, 0, stream>>>(xb, wqkvT, b_attn, nullptr,
                                                   qkvb, nullptr, 8192, 3072, 1024);
    // V transpose (sigma token order) for attention B-operand
    vtrans_kernel<<<dim3(32, 64), 256, 0, stream>>>(qkvb, vtb);
    // attention
    attn_kernel<<<dim3(32, 64), 256, 0, stream>>>(qkvb, vtb, attnb);
    // x1 = attn @ w_o + b_o + x
    gemm_bf16<2><<<dim3(64, 8), 256, 0, stream>>>(attnb, woT, b_o, x,
                                                  nullptr, x1, 8192, 1024, 1024);
    // h = LN(x1)
    ln_kernel<<<8192, 256, 0, stream>>>(x1, ln_w, ln_b, hb);
    // h1 = gelu(h @ w_fc1 + b_fc1)
    gemm_bf16<1><<<dim3(64, 32), 256, 0, stream>>>(hb, w1T, b_fc1, nullptr,
                                                   h1, nullptr, 8192, 4096, 1024);
    // out = h1 @ w_fc2 + b_fc2 + x1
    gemm_bf16<2><<<dim3(64, 8), 256, 0, stream>>>(h1, w2T, b_fc2, x1,
                                                  nullptr, out, 8192, 1024, 4096);
}

// Round 3
// 455.492 us; speedup vs baseline: 1.4344x; 1.1220x over previous
//
#include <hip/hip_runtime.h>
#include <hip/hip_bf16.h>
#include <math.h>
#include <stdint.h>

typedef __attribute__((ext_vector_type(8))) short s16x8;
typedef __attribute__((ext_vector_type(4))) float f32x4;
typedef unsigned int u32;
typedef unsigned short u16;

#define DEVINL __device__ __forceinline__

DEVINL u16 f2bf(float f) {
    u32 b = __builtin_bit_cast(u32, f);
    u32 r = (b + 0x7fffu + ((b >> 16) & 1u)) >> 16;
    return (u16)r;
}

DEVINL float fexp2(float x) {
    float r;
    asm("v_exp_f32 %0, %1" : "=v"(r) : "v"(x));
    return r;
}

DEVINL u32 cvt_pk_bf16(float lo, float hi) {
    u32 r;
    asm("v_cvt_pk_bf16_f32 %0, %1, %2" : "=v"(r) : "v"(lo), "v"(hi));
    return r;
}

DEVINL void gload_lds16(const void* g, const void* l) {
    __builtin_amdgcn_global_load_lds(
        (const __attribute__((address_space(1))) u32*)(uintptr_t)g,
        (__attribute__((address_space(3))) u32*)(uintptr_t)l, 16, 0, 0);
}

// ---------------- elementwise f32 -> bf16 ----------------
__global__ __launch_bounds__(256)
void cvt_bf16_kernel(const float* __restrict__ in, u16* __restrict__ out, int n4)
{
    int i = blockIdx.x * 256 + threadIdx.x;
    const int stride = gridDim.x * 256;
    for (; i < n4; i += stride) {
        float4 v = ((const float4*)in)[i];
        ushort4 o;
        o.x = f2bf(v.x); o.y = f2bf(v.y); o.z = f2bf(v.z); o.w = f2bf(v.w);
        ((ushort4*)out)[i] = o;
    }
}

// ------------- transpose + convert weights: src[R][C] f32 -> dst[C][R] bf16 -------------
__global__ __launch_bounds__(256)
void transpose_cvt(const float* __restrict__ src, u16* __restrict__ dst, int R, int C)
{
    __shared__ float tile[64][65];
    const int t = threadIdx.x;
    const int c0 = blockIdx.x * 64, r0 = blockIdx.y * 64;
    const int rr = t >> 6;   // 0..3
    const int cc = t & 63;
    #pragma unroll
    for (int i = 0; i < 16; ++i)
        tile[i * 4 + rr][cc] = src[(size_t)(r0 + i * 4 + rr) * C + c0 + cc];
    __syncthreads();
    #pragma unroll
    for (int i = 0; i < 16; ++i) {
        int orow = i * 4 + rr;           // source col
        dst[(size_t)(c0 + orow) * R + r0 + cc] = f2bf(tile[cc][orow]);
    }
}

// ------------- V transpose: qkv[B,T, 2048+h*64+d] bf16 -> vt[bh, d, sigma(t)] bf16 -------
__global__ __launch_bounds__(256)
void vtrans_kernel(const u16* __restrict__ qkv, u16* __restrict__ vt)
{
    __shared__ u16 tile[64][68];
    const int t = threadIdx.x;
    const int st = blockIdx.x;       // T/64
    const int bh = blockIdx.y;       // B*H
    const int b = bh >> 4, h = bh & 15;
    const int s0 = st * 64;
    const int rr = t >> 6, cc = t & 63;
    const int sc = (cc & 32) | (((cc & 15) >> 2) << 3) | ((cc & 3) << 1) | ((cc >> 4) & 1);
    #pragma unroll
    for (int i = 0; i < 16; ++i) {
        int s = i * 4 + rr;
        tile[s][cc] = qkv[(size_t)(b * 2048 + s0 + s) * 3072 + 2048 + h * 64 + cc];
    }
    __syncthreads();
    #pragma unroll
    for (int i = 0; i < 16; ++i) {
        int d = i * 4 + rr;
        vt[(size_t)(bh * 64 + d) * 2048 + s0 + sc] = tile[cc][d];
    }
}

// ============ deep-pipelined GEMM: C[M,N] = A[M,K] * B[N,K]^T + bias (+resid) ============
// BN=256 fixed, BK=64, 512 threads = 8 waves (2M x 4N). Per-wave out: (BM/2) x 64.
// LDS: 2 buffers, each {A[BM][64], B[256][64]} bf16, XOR-swizzled (row&7)<<4 bytes.
// Pipeline: at group-h start issue ALL loads for tile h+1 into idle buffer; loads stay
// in flight across per-phase raw barriers; drained by group-end __syncthreads (vmcnt0).
// MODE 0: bf16 out +bias | 1: bf16 out +bias+GELU | 2: f32 out +bias+resid
template<int BM, int MODE>
__global__ __launch_bounds__(512, 1)
void gemm8p(const u16* __restrict__ A, const u16* __restrict__ B,
            const float* __restrict__ bias, const float* __restrict__ resid,
            u16* __restrict__ obf, float* __restrict__ of32,
            int M, int N, int K)
{
    constexpr int MF = BM / 32;            // A-frags per wave (8 or 4)
    constexpr int NPH = MF / 2;            // phases per group (4 or 2)
    constexpr int ALOADS = BM / 64;        // gloads/thread for A per tile (4 or 2)
    constexpr int ABYTES = BM * 128;       // A tile bytes (rows * 64 cols * 2B)
    constexpr int BUFBYTES = ABYTES + 65536 / 2; // + B tile 256*128 = 32768
    extern __shared__ char lds[];

    const int t = threadIdx.x;
    const int lane = t & 63, w = t >> 6;
    const int wr = w >> 2, wc = w & 3;     // 2 x 4 wave grid
    const int g = lane >> 4, lr = lane & 15;
    const int bm = blockIdx.x * BM, bn = blockIdx.y * 256;

    // staging: thread t loads 16B; row (t>>3), pre-swizzled col
    const int srow = t >> 3;                              // 0..63
    const int scol = (((t & 7) ^ (srow & 7)) * 8);        // element col
    const u16* ag = A + (size_t)(bm + srow) * K + scol;
    const u16* bg = B + (size_t)(bn + srow) * K + scol;

    f32x4 acc[MF][4] = {};

    // prologue: stage tile 0 into buf0
    #pragma unroll
    for (int L = 0; L < ALOADS; ++L)
        gload_lds16(ag + (size_t)L * 64 * K, lds + L * 8192 + t * 16);
    #pragma unroll
    for (int L = 0; L < 4; ++L)
        gload_lds16(bg + (size_t)L * 64 * K, lds + ABYTES + L * 8192 + t * 16);
    __syncthreads();

    const int NK = K >> 6;
    const int xr = (lr & 7) << 4;          // read-side byte XOR

    for (int h = 0; h < NK; ++h) {
        char* cbuf = lds + (h & 1) * BUFBYTES;
        char* nbuf = lds + ((h + 1) & 1) * BUFBYTES;

        // issue next tile's loads first (4-phase in-flight window)
        if (h + 1 < NK) {
            const size_t ko = (size_t)(h + 1) * 64;
            #pragma unroll
            for (int L = 0; L < ALOADS; ++L)
                gload_lds16(ag + (size_t)L * 64 * K + ko, nbuf + L * 8192 + t * 16);
            #pragma unroll
            for (int L = 0; L < 4; ++L)
                gload_lds16(bg + (size_t)L * 64 * K + ko, nbuf + ABYTES + L * 8192 + t * 16);
        }

        // B fragments once per group (held in registers through all phases)
        s16x8 bf[4][2];
        #pragma unroll
        for (int nf = 0; nf < 4; ++nf) {
            const int brow = wc * 64 + nf * 16 + lr;
            #pragma unroll
            for (int ks = 0; ks < 2; ++ks)
                bf[nf][ks] = *(const s16x8*)(cbuf + ABYTES + brow * 128 + (((ks * 64 + g * 16)) ^ xr));
        }

        #pragma unroll
        for (int p = 0; p < NPH; ++p) {
            s16x8 af[2][2];
            #pragma unroll
            for (int mi = 0; mi < 2; ++mi) {
                const int arow = wr * (BM / 2) + (p * 2 + mi) * 16 + lr;
                #pragma unroll
                for (int ks = 0; ks < 2; ++ks)
                    af[mi][ks] = *(const s16x8*)(cbuf + arow * 128 + (((ks * 64 + g * 16)) ^ xr));
            }
            __builtin_amdgcn_sched_barrier(0);
            __builtin_amdgcn_s_barrier();          // phase entry
            __builtin_amdgcn_s_setprio(1);
            #pragma unroll
            for (int ks = 0; ks < 2; ++ks)
                #pragma unroll
                for (int mi = 0; mi < 2; ++mi)
                    #pragma unroll
                    for (int nf = 0; nf < 4; ++nf)
                        acc[p * 2 + mi][nf] = __builtin_amdgcn_mfma_f32_16x16x32_bf16(
                            af[mi][ks], bf[nf][ks], acc[p * 2 + mi][nf], 0, 0, 0);
            __builtin_amdgcn_s_setprio(0);
            __builtin_amdgcn_sched_barrier(0);
            if (p < NPH - 1) __builtin_amdgcn_s_barrier();   // phase exit
            else __syncthreads();                  // group end: vmcnt(0)+lgkmcnt(0)+barrier
        }
    }

    // epilogue
    #pragma unroll
    for (int mf = 0; mf < MF; ++mf) {
        const int rbase = bm + wr * (BM / 2) + mf * 16 + g * 4;
        #pragma unroll
        for (int nf = 0; nf < 4; ++nf) {
            const int col = bn + wc * 64 + nf * 16 + lr;
            const float bia = bias[col];
            #pragma unroll
            for (int b2 = 0; b2 < 4; ++b2) {
                const int r = rbase + b2;
                float v = acc[mf][nf][b2] + bia;
                if (MODE == 1) v = 0.5f * v * (1.0f + erff(v * 0.70710678118654752f));
                if (MODE == 2) {
                    v += resid[(size_t)r * N + col];
                    of32[(size_t)r * N + col] = v;
                } else {
                    obf[(size_t)r * N + col] = f2bf(v);
                }
            }
        }
    }
}

// ---------------- flash attention: one (b,h) x 64 Q rows per block ----------------
__global__ __launch_bounds__(256)
void attn_kernel(const u16* __restrict__ qkv, const u16* __restrict__ vt,
                 u16* __restrict__ attnb)
{
    __shared__ u16 Kls[64 * 64];
    __shared__ u16 Vls[64 * 64];
    __shared__ u32 Pls[4][16 * 36];   // per-wave P, packed bf16 pairs
    const int t = threadIdx.x, lane = t & 63, w = t >> 6;
    const int g = lane >> 4, lr = lane & 15;
    const int qt = blockIdx.x;         // T/64
    const int bh = blockIdx.y;         // B*H
    const int b = bh >> 4, h = bh & 15;

    const int qtok = b * 2048 + qt * 64 + w * 16 + lr;
    const u16* qp = qkv + (size_t)qtok * 3072 + h * 64;
    const s16x8 qf0 = *(const s16x8*)(qp + g * 8);
    const s16x8 qf1 = *(const s16x8*)(qp + 32 + g * 8);

    f32x4 o[4] = {};
    float lreg[4] = {0.f, 0.f, 0.f, 0.f};

    const int srow = t >> 3;                              // 0..31
    const int scol = (((t & 7) ^ (srow & 7)) * 8);        // swizzled element col
    const size_t kbase0 = (size_t)(b * 2048 + srow) * 3072 + 1024 + h * 64 + scol;
    const size_t kbase1 = (size_t)(b * 2048 + srow + 32) * 3072 + 1024 + h * 64 + scol;
    const size_t vbase0 = (size_t)(bh * 64 + srow) * 2048 + scol;
    const size_t vbase1 = (size_t)(bh * 64 + srow + 32) * 2048 + scol;
    u16* lK0 = &Kls[w * 512]; u16* lK1 = &Kls[2048 + w * 512];
    u16* lV0 = &Vls[w * 512]; u16* lV1 = &Vls[2048 + w * 512];

    const int xr = (lr & 7) * 8;
    const float C2 = 0.18033688011112042f;   // (1/8) * log2(e)

    for (int s0 = 0; s0 < 2048; s0 += 64) {
        __syncthreads();
        gload_lds16(qkv + kbase0 + (size_t)s0 * 3072, lK0);
        gload_lds16(qkv + kbase1 + (size_t)s0 * 3072, lK1);
        gload_lds16(vt + vbase0 + s0, lV0);
        gload_lds16(vt + vbase1 + s0, lV1);
        __syncthreads();

        f32x4 sv[4];
        #pragma unroll
        for (int n = 0; n < 4; ++n) {
            const int kr = (n * 16 + lr) * 64;
            const s16x8 k0v = *(const s16x8*)&Kls[kr + ((g * 8) ^ xr)];
            const s16x8 k1v = *(const s16x8*)&Kls[kr + ((32 + g * 8) ^ xr)];
            f32x4 z = {};
            z = __builtin_amdgcn_mfma_f32_16x16x32_bf16(qf0, k0v, z, 0, 0, 0);
            z = __builtin_amdgcn_mfma_f32_16x16x32_bf16(qf1, k1v, z, 0, 0, 0);
            sv[n] = z;
        }

        #pragma unroll
        for (int b2 = 0; b2 < 4; ++b2) {
            const float p0 = fexp2(sv[0][b2] * C2);
            const float p1 = fexp2(sv[1][b2] * C2);
            const float p2 = fexp2(sv[2][b2] * C2);
            const float p3 = fexp2(sv[3][b2] * C2);
            float sum = (p0 + p1) + (p2 + p3);
            sum += __shfl_xor(sum, 1);
            sum += __shfl_xor(sum, 2);
            sum += __shfl_xor(sum, 4);
            sum += __shfl_xor(sum, 8);
            lreg[b2] += sum;
            const int prow = (g * 4 + b2) * 36;
            Pls[w][prow + lr]      = cvt_pk_bf16(p0, p1);
            Pls[w][prow + 16 + lr] = cvt_pk_bf16(p2, p3);
        }

        const s16x8 ap0 = *(const s16x8*)&Pls[w][lr * 36 + g * 4];
        const s16x8 ap1 = *(const s16x8*)&Pls[w][lr * 36 + 16 + g * 4];
        #pragma unroll
        for (int n = 0; n < 4; ++n) {
            const int vr = (n * 16 + lr) * 64;
            const s16x8 v0 = *(const s16x8*)&Vls[vr + ((g * 8) ^ xr)];
            const s16x8 v1 = *(const s16x8*)&Vls[vr + ((32 + g * 8) ^ xr)];
            o[n] = __builtin_amdgcn_mfma_f32_16x16x32_bf16(ap0, v0, o[n], 0, 0, 0);
            o[n] = __builtin_amdgcn_mfma_f32_16x16x32_bf16(ap1, v1, o[n], 0, 0, 0);
        }
    }

    const int orow0 = b * 2048 + qt * 64 + w * 16 + g * 4;
    #pragma unroll
    for (int b2 = 0; b2 < 4; ++b2) {
        const float inv = 1.0f / lreg[b2];
        #pragma unroll
        for (int n = 0; n < 4; ++n)
            attnb[(size_t)(orow0 + b2) * 1024 + h * 64 + n * 16 + lr] = f2bf(o[n][b2] * inv);
    }
}

// ---------------- LayerNorm: f32 in -> bf16 out ----------------
__global__ __launch_bounds__(256)
void ln_kernel(const float* __restrict__ x, const float* __restrict__ lw,
               const float* __restrict__ lb, u16* __restrict__ out)
{
    const int row = blockIdx.x;
    const int t = threadIdx.x;
    const float4 v = ((const float4*)(x + (size_t)row * 1024))[t];
    float s = v.x + v.y + v.z + v.w;
    float s2 = v.x * v.x + v.y * v.y + v.z * v.z + v.w * v.w;
    #pragma unroll
    for (int m = 32; m >= 1; m >>= 1) {
        s  += __shfl_xor(s, m);
        s2 += __shfl_xor(s2, m);
    }
    __shared__ float red[16];
    const int w = t >> 6, lane = t & 63;
    if (lane == 0) { red[w] = s; red[8 + w] = s2; }
    __syncthreads();
    s  = red[0] + red[1] + red[2] + red[3];
    s2 = red[8] + red[9] + red[10] + red[11];
    const float mu = s * (1.0f / 1024.0f);
    const float var = s2 * (1.0f / 1024.0f) - mu * mu;
    const float inv = rsqrtf(var + 1e-5f);
    const float4 wv = ((const float4*)lw)[t];
    const float4 bv = ((const float4*)lb)[t];
    ushort4 oo;
    oo.x = f2bf((v.x - mu) * inv * wv.x + bv.x);
    oo.y = f2bf((v.y - mu) * inv * wv.y + bv.y);
    oo.z = f2bf((v.z - mu) * inv * wv.z + bv.z);
    oo.w = f2bf((v.w - mu) * inv * wv.w + bv.w);
    ((ushort4*)(out + (size_t)row * 1024))[t] = oo;
}

extern "C" void kernel_launch(void* const* d_in, const int* in_sizes, int n_in,
                              void* d_out, int out_size, void* d_ws, size_t ws_size,
                              hipStream_t stream)
{
    const float* x      = (const float*)d_in[0];
    const float* w_attn = (const float*)d_in[1];
    const float* b_attn = (const float*)d_in[2];
    const float* w_o    = (const float*)d_in[3];
    const float* b_o    = (const float*)d_in[4];
    const float* ln_w   = (const float*)d_in[5];
    const float* ln_b   = (const float*)d_in[6];
    const float* w_fc1  = (const float*)d_in[7];
    const float* b_fc1  = (const float*)d_in[8];
    const float* w_fc2  = (const float*)d_in[9];
    const float* b_fc2  = (const float*)d_in[10];
    float* out = (float*)d_out;

    char* ws = (char*)d_ws;
    u16*   xb    = (u16*)(ws);                       // 16 MB  bf16 x
    u16*   wqkvT = (u16*)(ws + 16777216);            //  6 MB  [3072][1024]
    u16*   woT   = (u16*)(ws + 23068672);            //  2 MB  [1024][1024]
    u16*   w1T   = (u16*)(ws + 25165824);            //  8 MB  [4096][1024]
    u16*   w2T   = (u16*)(ws + 33554432);            //  8 MB  [1024][4096]
    float* x1    = (float*)(ws + 41943040);          // 32 MB  f32 residual-1
    u16*   attnb = (u16*)(ws + 75497472);            // 16 MB  (later reused as hb)
    u16*   hb    = attnb;
    u16*   qkvb  = (u16*)(ws + 92274688);            // 48 MB  [8192][3072]
    u16*   vtb   = qkvb + 25165824;                  // 16 MB  [64][64][2048]
    u16*   h1    = qkvb;                             // 64 MB alias (qkv+vt dead after attn)

    cvt_bf16_kernel<<<2048, 256, 0, stream>>>(x, xb, 8192 * 1024 / 4);
    transpose_cvt<<<dim3(48, 16), 256, 0, stream>>>(w_attn, wqkvT, 1024, 3072);
    transpose_cvt<<<dim3(16, 16), 256, 0, stream>>>(w_o,   woT,  1024, 1024);
    transpose_cvt<<<dim3(64, 16), 256, 0, stream>>>(w_fc1, w1T,  1024, 4096);
    transpose_cvt<<<dim3(16, 64), 256, 0, stream>>>(w_fc2, w2T,  4096, 1024);

    // qkv = x @ w_attn + b_attn      [BM=256: LDS 128KB]
    gemm8p<256, 0><<<dim3(32, 12), 512, 131072, stream>>>(xb, wqkvT, b_attn, nullptr,
                                                          qkvb, nullptr, 8192, 3072, 1024);
    vtrans_kernel<<<dim3(32, 64), 256, 0, stream>>>(qkvb, vtb);
    attn_kernel<<<dim3(32, 64), 256, 0, stream>>>(qkvb, vtb, attnb);
    // x1 = attn @ w_o + b_o + x      [BM=128 -> grid 256, full chip; LDS 96KB]
    gemm8p<128, 2><<<dim3(64, 4), 512, 98304, stream>>>(attnb, woT, b_o, x,
                                                        nullptr, x1, 8192, 1024, 1024);
    ln_kernel<<<8192, 256, 0, stream>>>(x1, ln_w, ln_b, hb);
    // h1 = gelu(h @ w_fc1 + b_fc1)
    gemm8p<256, 1><<<dim3(32, 16), 512, 131072, stream>>>(hb, w1T, b_fc1, nullptr,
                                                          h1, nullptr, 8192, 4096, 1024);
    // out = h1 @ w_fc2 + b_fc2 + x1
    gemm8p<128, 2><<<dim3(64, 4), 512, 98304, stream>>>(h1, w2T, b_fc2, x1,
                                                        nullptr, out, 8192, 1024, 4096);
}

// Round 4
// 416.114 us; speedup vs baseline: 1.5702x; 1.0946x over previous
//
#include <hip/hip_runtime.h>
#include <hip/hip_bf16.h>
#include <math.h>
#include <stdint.h>

typedef __attribute__((ext_vector_type(8))) short s16x8;
typedef __attribute__((ext_vector_type(4))) float f32x4;
typedef __attribute__((ext_vector_type(4))) u_int32_t u32x4;
typedef unsigned int u32;
typedef unsigned short u16;

#define DEVINL __device__ __forceinline__

DEVINL u16 f2bf(float f) {
    u32 b = __builtin_bit_cast(u32, f);
    u32 r = (b + 0x7fffu + ((b >> 16) & 1u)) >> 16;
    return (u16)r;
}

DEVINL float fexp2(float x) {
    float r;
    asm("v_exp_f32 %0, %1" : "=v"(r) : "v"(x));
    return r;
}

DEVINL u32 cvt_pk_bf16(float lo, float hi) {
    u32 r;
    asm("v_cvt_pk_bf16_f32 %0, %1, %2" : "=v"(r) : "v"(lo), "v"(hi));
    return r;
}

DEVINL void gload_lds16(const void* g, const void* l) {
    __builtin_amdgcn_global_load_lds(
        (const __attribute__((address_space(1))) u32*)(uintptr_t)g,
        (__attribute__((address_space(3))) u32*)(uintptr_t)l, 16, 0, 0);
}

// ---------------- elementwise f32 -> bf16 ----------------
__global__ __launch_bounds__(256)
void cvt_bf16_kernel(const float* __restrict__ in, u16* __restrict__ out, int n4)
{
    int i = blockIdx.x * 256 + threadIdx.x;
    const int stride = gridDim.x * 256;
    for (; i < n4; i += stride) {
        float4 v = ((const float4*)in)[i];
        ushort4 o;
        o.x = f2bf(v.x); o.y = f2bf(v.y); o.z = f2bf(v.z); o.w = f2bf(v.w);
        ((ushort4*)out)[i] = o;
    }
}

// ------------- transpose + convert weights: src[R][C] f32 -> dst[C][R] bf16 -------------
__global__ __launch_bounds__(256)
void transpose_cvt(const float* __restrict__ src, u16* __restrict__ dst, int R, int C)
{
    __shared__ float tile[64][65];
    const int t = threadIdx.x;
    const int c0 = blockIdx.x * 64, r0 = blockIdx.y * 64;
    const int rr = t >> 6;   // 0..3
    const int cc = t & 63;
    #pragma unroll
    for (int i = 0; i < 16; ++i)
        tile[i * 4 + rr][cc] = src[(size_t)(r0 + i * 4 + rr) * C + c0 + cc];
    __syncthreads();
    #pragma unroll
    for (int i = 0; i < 16; ++i) {
        int orow = i * 4 + rr;           // source col
        dst[(size_t)(c0 + orow) * R + r0 + cc] = f2bf(tile[cc][orow]);
    }
}

// ------------- V transpose: qkv[B,T, 2048+h*64+d] bf16 -> vt[bh, d, sigma(t)] bf16 -------
// sigma: token cc stored at position matching the in-register packed-P virtual k-order:
// n=cc>>4, g=(cc>>2)&3, b2=cc&3  ->  v = (n>>1)*32 + g*8 + (n&1)*4 + b2
__global__ __launch_bounds__(256)
void vtrans_kernel(const u16* __restrict__ qkv, u16* __restrict__ vt)
{
    __shared__ u16 tile[64][68];
    const int t = threadIdx.x;
    const int st = blockIdx.x;       // T/64
    const int bh = blockIdx.y;       // B*H
    const int b = bh >> 4, h = bh & 15;
    const int s0 = st * 64;
    const int rr = t >> 6, cc = t & 63;
    const int sc = (cc & 32) | (((cc >> 2) & 3) << 3) | (((cc >> 4) & 1) << 2) | (cc & 3);
    #pragma unroll
    for (int i = 0; i < 16; ++i) {
        int s = i * 4 + rr;
        tile[s][cc] = qkv[(size_t)(b * 2048 + s0 + s) * 3072 + 2048 + h * 64 + cc];
    }
    __syncthreads();
    #pragma unroll
    for (int i = 0; i < 16; ++i) {
        int d = i * 4 + rr;
        vt[(size_t)(bh * 64 + d) * 2048 + s0 + sc] = tile[cc][d];
    }
}

// ============ deep-pipelined GEMM: C[M,N] = A[M,K] * B[N,K]^T + bias (+resid) ============
// BN=256 fixed, BK=64, 512 threads = 8 waves (2M x 4N). Per-wave out: (BM/2) x 64.
// MODE 0: bf16 out +bias | 1: bf16 out +bias+GELU | 2: f32 out +bias+resid
// QSC: scale cols<1024 by (1/8)*log2e (folds attention softmax scale into Q)
template<int BM, int MODE, int QSC>
__global__ __launch_bounds__(512, 1)
void gemm8p(const u16* __restrict__ A, const u16* __restrict__ B,
            const float* __restrict__ bias, const float* __restrict__ resid,
            u16* __restrict__ obf, float* __restrict__ of32,
            int M, int N, int K)
{
    constexpr int MF = BM / 32;
    constexpr int NPH = MF / 2;
    constexpr int ALOADS = BM / 64;
    constexpr int ABYTES = BM * 128;
    constexpr int BUFBYTES = ABYTES + 32768;
    extern __shared__ char lds[];

    const int t = threadIdx.x;
    const int lane = t & 63, w = t >> 6;
    const int wr = w >> 2, wc = w & 3;
    const int g = lane >> 4, lr = lane & 15;
    const int bm = blockIdx.x * BM, bn = blockIdx.y * 256;

    const int srow = t >> 3;                              // 0..63
    const int scol = (((t & 7) ^ (srow & 7)) * 8);        // pre-swizzled element col
    const u16* ag = A + (size_t)(bm + srow) * K + scol;
    const u16* bg = B + (size_t)(bn + srow) * K + scol;

    f32x4 acc[MF][4] = {};

    #pragma unroll
    for (int L = 0; L < ALOADS; ++L)
        gload_lds16(ag + (size_t)L * 64 * K, lds + L * 8192 + t * 16);
    #pragma unroll
    for (int L = 0; L < 4; ++L)
        gload_lds16(bg + (size_t)L * 64 * K, lds + ABYTES + L * 8192 + t * 16);
    __syncthreads();

    const int NK = K >> 6;
    const int xr = (lr & 7) << 4;

    for (int h = 0; h < NK; ++h) {
        char* cbuf = lds + (h & 1) * BUFBYTES;
        char* nbuf = lds + ((h + 1) & 1) * BUFBYTES;

        if (h + 1 < NK) {
            const size_t ko = (size_t)(h + 1) * 64;
            #pragma unroll
            for (int L = 0; L < ALOADS; ++L)
                gload_lds16(ag + (size_t)L * 64 * K + ko, nbuf + L * 8192 + t * 16);
            #pragma unroll
            for (int L = 0; L < 4; ++L)
                gload_lds16(bg + (size_t)L * 64 * K + ko, nbuf + ABYTES + L * 8192 + t * 16);
        }

        s16x8 bf[4][2];
        #pragma unroll
        for (int nf = 0; nf < 4; ++nf) {
            const int brow = wc * 64 + nf * 16 + lr;
            #pragma unroll
            for (int ks = 0; ks < 2; ++ks)
                bf[nf][ks] = *(const s16x8*)(cbuf + ABYTES + brow * 128 + ((ks * 64 + g * 16) ^ xr));
        }

        #pragma unroll
        for (int p = 0; p < NPH; ++p) {
            s16x8 af[2][2];
            #pragma unroll
            for (int mi = 0; mi < 2; ++mi) {
                const int arow = wr * (BM / 2) + (p * 2 + mi) * 16 + lr;
                #pragma unroll
                for (int ks = 0; ks < 2; ++ks)
                    af[mi][ks] = *(const s16x8*)(cbuf + arow * 128 + ((ks * 64 + g * 16) ^ xr));
            }
            __builtin_amdgcn_sched_barrier(0);
            __builtin_amdgcn_s_barrier();
            __builtin_amdgcn_s_setprio(1);
            #pragma unroll
            for (int ks = 0; ks < 2; ++ks)
                #pragma unroll
                for (int mi = 0; mi < 2; ++mi)
                    #pragma unroll
                    for (int nf = 0; nf < 4; ++nf)
                        acc[p * 2 + mi][nf] = __builtin_amdgcn_mfma_f32_16x16x32_bf16(
                            af[mi][ks], bf[nf][ks], acc[p * 2 + mi][nf], 0, 0, 0);
            __builtin_amdgcn_s_setprio(0);
            __builtin_amdgcn_sched_barrier(0);
            if (p < NPH - 1) __builtin_amdgcn_s_barrier();
            else __syncthreads();
        }
    }

    #pragma unroll
    for (int mf = 0; mf < MF; ++mf) {
        const int rbase = bm + wr * (BM / 2) + mf * 16 + g * 4;
        #pragma unroll
        for (int nf = 0; nf < 4; ++nf) {
            const int col = bn + wc * 64 + nf * 16 + lr;
            const float bia = bias[col];
            #pragma unroll
            for (int b2 = 0; b2 < 4; ++b2) {
                const int r = rbase + b2;
                float v = acc[mf][nf][b2] + bia;
                if (QSC && col < 1024) v *= 0.18033688011112042f;
                if (MODE == 1) v = 0.5f * v * (1.0f + erff(v * 0.70710678118654752f));
                if (MODE == 2) {
                    v += resid[(size_t)r * N + col];
                    of32[(size_t)r * N + col] = v;
                } else {
                    obf[(size_t)r * N + col] = f2bf(v);
                }
            }
        }
    }
}

// ---------------- flash attention v2: swapped QK^T, in-register P, 2-phase pipeline ------
// Block = 64 q-rows of one (b,h); 4 waves x 16 rows. K/V double-buffered, XOR-swizzled.
// sv[n][b2] = S[token=16n+4g+b2][qrow=lr]; P packed in-register to PV A-operand.
__global__ __launch_bounds__(256)
void attn_kernel(const u16* __restrict__ qkv, const u16* __restrict__ vt,
                 u16* __restrict__ attnb)
{
    __shared__ u16 Kls[2][4096];
    __shared__ u16 Vls[2][4096];
    const int t = threadIdx.x, lane = t & 63, w = t >> 6;
    const int g = lane >> 4, lr = lane & 15;
    // XCD swizzle: each XCD owns 8 complete (b,h) heads
    const int wg = blockIdx.x;
    const int xcd = wg & 7, slot = wg >> 3;
    const int bh = xcd * 8 + (slot >> 5);
    const int qt = slot & 31;
    const int b = bh >> 4, h = bh & 15;

    // staging geometry: 8 lanes/row, 16B/lane, pre-swizzled source col
    const int srow = t >> 3;                              // 0..31
    const int scol = (((t & 7) ^ (srow & 7)) * 8);
    const u16* kg0 = qkv + (size_t)(b * 2048 + srow) * 3072 + 1024 + h * 64 + scol;
    const u16* kg1 = qkv + (size_t)(b * 2048 + srow + 32) * 3072 + 1024 + h * 64 + scol;
    const u16* vg0 = vt + (size_t)(bh * 64 + srow) * 2048 + scol;
    const u16* vg1 = vt + (size_t)(bh * 64 + srow + 32) * 2048 + scol;
    const int ldst = w * 512;   // per-wave contiguous 1KB dest (u16 elements)

    // stage tile 0
    gload_lds16(kg0, &Kls[0][ldst]);
    gload_lds16(kg1, &Kls[0][2048 + ldst]);
    gload_lds16(vg0, &Vls[0][ldst]);
    gload_lds16(vg1, &Vls[0][2048 + ldst]);

    // Q fragments (B-operand: lane holds Q[col=lr][k=ks*32+g*8+j]); Q pre-scaled by qkv GEMM
    const int qtok = b * 2048 + qt * 64 + w * 16 + lr;
    const u16* qp = qkv + (size_t)qtok * 3072 + h * 64;
    const s16x8 qf0 = *(const s16x8*)(qp + g * 8);
    const s16x8 qf1 = *(const s16x8*)(qp + 32 + g * 8);

    f32x4 o[4] = {};
    float psum = 0.f;
    const int xr = (lr & 7) * 8;

    for (int s = 0; s < 32; ++s) {
        const int cur = s & 1;
        __syncthreads();                 // tile s landed; buf cur^1 free
        if (s + 1 < 32) {
            const size_t ko = (size_t)(s + 1) * 64;
            gload_lds16(kg0 + ko * 3072, &Kls[cur ^ 1][ldst]);
            gload_lds16(kg1 + ko * 3072, &Kls[cur ^ 1][2048 + ldst]);
            gload_lds16(vg0 + ko, &Vls[cur ^ 1][ldst]);
            gload_lds16(vg1 + ko, &Vls[cur ^ 1][2048 + ldst]);
        }

        // S^T = K Q^T : sv[n][b2] = S[token=16n+4g+b2][qrow=lr]
        f32x4 sv[4];
        #pragma unroll
        for (int n = 0; n < 4; ++n) {
            const int kr = (n * 16 + lr) * 64;
            const s16x8 k0v = *(const s16x8*)&Kls[cur][kr + ((g * 8) ^ xr)];
            const s16x8 k1v = *(const s16x8*)&Kls[cur][kr + ((32 + g * 8) ^ xr)];
            f32x4 z = {};
            z = __builtin_amdgcn_mfma_f32_16x16x32_bf16(k0v, qf0, z, 0, 0, 0);
            z = __builtin_amdgcn_mfma_f32_16x16x32_bf16(k1v, qf1, z, 0, 0, 0);
            sv[n] = z;
        }

        // max-free softmax: p = exp2(S * c) (scale pre-folded into Q); per-lane partial sums
        float p[4][4];
        #pragma unroll
        for (int n = 0; n < 4; ++n) {
            #pragma unroll
            for (int b2 = 0; b2 < 4; ++b2)
                p[n][b2] = fexp2(sv[n][b2]);
            psum += (p[n][0] + p[n][1]) + (p[n][2] + p[n][3]);
        }

        // pack P to PV A-operands (virtual k-order matches V's sigma)
        u32x4 pk0, pk1;
        pk0[0] = cvt_pk_bf16(p[0][0], p[0][1]);
        pk0[1] = cvt_pk_bf16(p[0][2], p[0][3]);
        pk0[2] = cvt_pk_bf16(p[1][0], p[1][1]);
        pk0[3] = cvt_pk_bf16(p[1][2], p[1][3]);
        pk1[0] = cvt_pk_bf16(p[2][0], p[2][1]);
        pk1[1] = cvt_pk_bf16(p[2][2], p[2][3]);
        pk1[2] = cvt_pk_bf16(p[3][0], p[3][1]);
        pk1[3] = cvt_pk_bf16(p[3][2], p[3][3]);
        const s16x8 pa0 = __builtin_bit_cast(s16x8, pk0);
        const s16x8 pa1 = __builtin_bit_cast(s16x8, pk1);

        // O += P V
        #pragma unroll
        for (int n = 0; n < 4; ++n) {
            const int vr = (n * 16 + lr) * 64;
            const s16x8 v0 = *(const s16x8*)&Vls[cur][vr + ((g * 8) ^ xr)];
            const s16x8 v1 = *(const s16x8*)&Vls[cur][vr + ((32 + g * 8) ^ xr)];
            o[n] = __builtin_amdgcn_mfma_f32_16x16x32_bf16(pa0, v0, o[n], 0, 0, 0);
            o[n] = __builtin_amdgcn_mfma_f32_16x16x32_bf16(pa1, v1, o[n], 0, 0, 0);
        }
    }

    // row sums: combine the 4 g-groups, then fetch row (g*4+b2)'s sum
    psum += __shfl_xor(psum, 16);
    psum += __shfl_xor(psum, 32);        // all lanes now hold L[lr]
    const int orow0 = b * 2048 + qt * 64 + w * 16 + g * 4;
    #pragma unroll
    for (int b2 = 0; b2 < 4; ++b2) {
        const float inv = 1.0f / __shfl(psum, g * 4 + b2);
        #pragma unroll
        for (int n = 0; n < 4; ++n)
            attnb[(size_t)(orow0 + b2) * 1024 + h * 64 + n * 16 + lr] = f2bf(o[n][b2] * inv);
    }
}

// ---------------- LayerNorm: f32 in -> bf16 out ----------------
__global__ __launch_bounds__(256)
void ln_kernel(const float* __restrict__ x, const float* __restrict__ lw,
               const float* __restrict__ lb, u16* __restrict__ out)
{
    const int row = blockIdx.x;
    const int t = threadIdx.x;
    const float4 v = ((const float4*)(x + (size_t)row * 1024))[t];
    float s = v.x + v.y + v.z + v.w;
    float s2 = v.x * v.x + v.y * v.y + v.z * v.z + v.w * v.w;
    #pragma unroll
    for (int m = 32; m >= 1; m >>= 1) {
        s  += __shfl_xor(s, m);
        s2 += __shfl_xor(s2, m);
    }
    __shared__ float red[16];
    const int w = t >> 6, lane = t & 63;
    if (lane == 0) { red[w] = s; red[8 + w] = s2; }
    __syncthreads();
    s  = red[0] + red[1] + red[2] + red[3];
    s2 = red[8] + red[9] + red[10] + red[11];
    const float mu = s * (1.0f / 1024.0f);
    const float var = s2 * (1.0f / 1024.0f) - mu * mu;
    const float inv = rsqrtf(var + 1e-5f);
    const float4 wv = ((const float4*)lw)[t];
    const float4 bv = ((const float4*)lb)[t];
    ushort4 oo;
    oo.x = f2bf((v.x - mu) * inv * wv.x + bv.x);
    oo.y = f2bf((v.y - mu) * inv * wv.y + bv.y);
    oo.z = f2bf((v.z - mu) * inv * wv.z + bv.z);
    oo.w = f2bf((v.w - mu) * inv * wv.w + bv.w);
    ((ushort4*)(out + (size_t)row * 1024))[t] = oo;
}

extern "C" void kernel_launch(void* const* d_in, const int* in_sizes, int n_in,
                              void* d_out, int out_size, void* d_ws, size_t ws_size,
                              hipStream_t stream)
{
    const float* x      = (const float*)d_in[0];
    const float* w_attn = (const float*)d_in[1];
    const float* b_attn = (const float*)d_in[2];
    const float* w_o    = (const float*)d_in[3];
    const float* b_o    = (const float*)d_in[4];
    const float* ln_w   = (const float*)d_in[5];
    const float* ln_b   = (const float*)d_in[6];
    const float* w_fc1  = (const float*)d_in[7];
    const float* b_fc1  = (const float*)d_in[8];
    const float* w_fc2  = (const float*)d_in[9];
    const float* b_fc2  = (const float*)d_in[10];
    float* out = (float*)d_out;

    char* ws = (char*)d_ws;
    u16*   xb    = (u16*)(ws);                       // 16 MB  bf16 x
    u16*   wqkvT = (u16*)(ws + 16777216);            //  6 MB  [3072][1024]
    u16*   woT   = (u16*)(ws + 23068672);            //  2 MB  [1024][1024]
    u16*   w1T   = (u16*)(ws + 25165824);            //  8 MB  [4096][1024]
    u16*   w2T   = (u16*)(ws + 33554432);            //  8 MB  [1024][4096]
    float* x1    = (float*)(ws + 41943040);          // 32 MB  f32 residual-1
    u16*   attnb = (u16*)(ws + 75497472);            // 16 MB  (later reused as hb)
    u16*   hb    = attnb;
    u16*   qkvb  = (u16*)(ws + 92274688);            // 48 MB  [8192][3072]
    u16*   vtb   = qkvb + 25165824;                  // 16 MB  [64][64][2048]
    u16*   h1    = qkvb;                             // 64 MB alias (qkv+vt dead after attn)

    cvt_bf16_kernel<<<2048, 256, 0, stream>>>(x, xb, 8192 * 1024 / 4);
    transpose_cvt<<<dim3(48, 16), 256, 0, stream>>>(w_attn, wqkvT, 1024, 3072);
    transpose_cvt<<<dim3(16, 16), 256, 0, stream>>>(w_o,   woT,  1024, 1024);
    transpose_cvt<<<dim3(64, 16), 256, 0, stream>>>(w_fc1, w1T,  1024, 4096);
    transpose_cvt<<<dim3(16, 64), 256, 0, stream>>>(w_fc2, w2T,  4096, 1024);

    // qkv = x @ w_attn + b_attn   [BM=128 -> grid 768 = 3 clean waves; Q cols pre-scaled]
    gemm8p<128, 0, 1><<<dim3(64, 12), 512, 98304, stream>>>(xb, wqkvT, b_attn, nullptr,
                                                            qkvb, nullptr, 8192, 3072, 1024);
    vtrans_kernel<<<dim3(32, 64), 256, 0, stream>>>(qkvb, vtb);
    attn_kernel<<<2048, 256, 0, stream>>>(qkvb, vtb, attnb);
    // x1 = attn @ w_o + b_o + x
    gemm8p<128, 2, 0><<<dim3(64, 4), 512, 98304, stream>>>(attnb, woT, b_o, x,
                                                           nullptr, x1, 8192, 1024, 1024);
    ln_kernel<<<8192, 256, 0, stream>>>(x1, ln_w, ln_b, hb);
    // h1 = gelu(h @ w_fc1 + b_fc1)
    gemm8p<256, 1, 0><<<dim3(32, 16), 512, 131072, stream>>>(hb, w1T, b_fc1, nullptr,
                                                             h1, nullptr, 8192, 4096, 1024);
    // out = h1 @ w_fc2 + b_fc2 + x1
    gemm8p<128, 2, 0><<<dim3(64, 4), 512, 98304, stream>>>(h1, w2T, b_fc2, x1,
                                                           nullptr, out, 8192, 1024, 4096);
}